// Round 3
// baseline (117.204 us; speedup 1.0000x reference)
//
#include <hip/hip_runtime.h>
#include <hip/hip_cooperative_groups.h>

namespace cg = cooperative_groups;

typedef unsigned short ushort_t;
typedef __bf16 bf16x8 __attribute__((ext_vector_type(8)));
typedef float f32x4 __attribute__((ext_vector_type(4)));

static __device__ __forceinline__ ushort_t f2bf(float f) {
    __bf16 b = (__bf16)f;   // RNE convert
    return __builtin_bit_cast(ushort_t, b);
}

#define GLOAD_LDS16(gptr, lptr)                                                        \
    __builtin_amdgcn_global_load_lds(                                                  \
        (const __attribute__((address_space(1))) void*)(gptr),                         \
        (__attribute__((address_space(3))) void*)(lptr), 16, 0, 0)

// One cooperative kernel, 256 blocks x 512 threads (1 block/CU):
//   phase 1: x->bf16, w_out->bf16, Pt = (w_in v-rows)^T bf16, bfused
//   phase 2: Wf = w_out @ Wv^T          (64x64 tile per block)
//   phase 3: out = x @ Wf^T + bfused    (128x128 tile, XCD-swizzled)
__global__ __launch_bounds__(512)
void fused(const float* __restrict__ x, const float* __restrict__ w_in,
           const float* __restrict__ b_in, const float* __restrict__ w_out,
           const float* __restrict__ b_out,
           ushort_t* __restrict__ xb, ushort_t* __restrict__ wob,
           ushort_t* __restrict__ Pt, ushort_t* __restrict__ Wfb,
           float* __restrict__ bfused, float* __restrict__ out) {
    __shared__ alignas(16) char smem[16640];   // max(tile 8320, g1 8KB, g2 16KB)

    const int b    = blockIdx.x;
    const int t    = threadIdx.x;
    const int lane = t & 63;
    const int wv   = t >> 6;        // 0..7
    const int fr   = lane & 15;
    const int fq   = lane >> 4;

    // ---------------- phase 1: conversions + gather + bias ----------------
    {
        // (a) x fp32 -> bf16: 1,048,576 float4 / 256 blocks = 4096/block
        #pragma unroll
        for (int p = 0; p < 8; ++p) {
            int i = b * 4096 + p * 512 + t;
            float4 v = ((const float4*)x)[i];
            ushort4 o; o.x = f2bf(v.x); o.y = f2bf(v.y); o.z = f2bf(v.z); o.w = f2bf(v.w);
            ((ushort4*)xb)[i] = o;
        }
        // (b) w_out fp32 -> bf16: 262,144 float4 -> 1024/block
        #pragma unroll
        for (int p = 0; p < 2; ++p) {
            int i = b * 1024 + p * 512 + t;
            float4 v = ((const float4*)w_out)[i];
            ushort4 o; o.x = f2bf(v.x); o.y = f2bf(v.y); o.z = f2bf(v.z); o.w = f2bf(v.w);
            ((ushort4*)wob)[i] = o;
        }
        // (d) bfused[row] = b_out[row] + sum_j w_out[row][j]*b_in[r(j)]; 4 rows/block
        if (wv < 4) {
            const int row = b * 4 + wv;
            float s = 0.f;
            #pragma unroll
            for (int it = 0; it < 16; ++it) {
                int j = it * 64 + lane;
                int r = (j >> 6) * 192 + 128 + (j & 63);
                s += w_out[(size_t)row * 1024 + j] * b_in[r];
            }
            #pragma unroll
            for (int off = 32; off; off >>= 1) s += __shfl_down(s, off, 64);
            if (lane == 0) bfused[row] = s + b_out[row];
        }
        // (c) Pt[c][j] = bf16(w_in[r(j)][c]); one 64x64 tile per block
        ushort_t (*tile)[65] = (ushort_t(*)[65])smem;
        const int gx = b & 15, gy = b >> 4;
        #pragma unroll
        for (int p = 0; p < 8; ++p) {
            int e = p * 512 + t;
            int j = e >> 6, c = e & 63;
            tile[j][c] = f2bf(w_in[(size_t)(gx * 192 + 128 + j) * 1024 + gy * 64 + c]);
        }
        __syncthreads();
        #pragma unroll
        for (int p = 0; p < 8; ++p) {
            int e = p * 512 + t;
            int c = e >> 6, j = e & 63;
            Pt[(size_t)(gy * 64 + c) * 1024 + gx * 64 + j] = tile[j][c];
        }
    }

    cg::this_grid().sync();

    // ---------------- phase 2: Wf = wob @ Pt^T (M=N=K=1024, 64x64 tiles) ----------------
    {
        ushort_t* lsA = (ushort_t*)smem;           // 64x32
        ushort_t* lsB = (ushort_t*)smem + 2048;
        const int tx = b & 15, ty = b >> 4;
        const int rA = ty * 64, rB = tx * 64;
        const int wr = wv >> 2, wc = wv & 3;       // 2x4 waves -> WM=32, WN=16
        f32x4 acc[2] = {};
        for (int k0 = 0; k0 < 1024; k0 += 32) {
            if (t < 256) {   // waves 0-3 stage A (256 chunks of 16B)
                const int c = t;
                GLOAD_LDS16(wob + (size_t)(rA + (c >> 2)) * 1024 + k0 + (c & 3) * 8,
                            &lsA[wv * 512]);
            } else {         // waves 4-7 stage B
                const int c = t - 256;
                GLOAD_LDS16(Pt + (size_t)(rB + (c >> 2)) * 1024 + k0 + (c & 3) * 8,
                            &lsB[(wv - 4) * 512]);
            }
            __syncthreads();
            bf16x8 af0 = *(const bf16x8*)&lsA[(wr * 32 + fr) * 32 + fq * 8];
            bf16x8 af1 = *(const bf16x8*)&lsA[(wr * 32 + 16 + fr) * 32 + fq * 8];
            bf16x8 bf  = *(const bf16x8*)&lsB[(wc * 16 + fr) * 32 + fq * 8];
            acc[0] = __builtin_amdgcn_mfma_f32_16x16x32_bf16(af0, bf, acc[0], 0, 0, 0);
            acc[1] = __builtin_amdgcn_mfma_f32_16x16x32_bf16(af1, bf, acc[1], 0, 0, 0);
            __syncthreads();
        }
        const int orow0 = rA + wr * 32 + fq * 4;
        const int ocol  = rB + wc * 16 + fr;
        #pragma unroll
        for (int i = 0; i < 2; ++i)
            #pragma unroll
            for (int r = 0; r < 4; ++r)
                Wfb[(size_t)(orow0 + i * 16 + r) * 1024 + ocol] = f2bf(acc[i][r]);
    }

    cg::this_grid().sync();

    // ---------------- phase 3: out = xb @ Wfb^T + bfused (M=4096,N=1024) ----------------
    {
        ushort_t* lsA = (ushort_t*)smem;           // 128x32
        ushort_t* lsB = (ushort_t*)smem + 4096;
        // XCD swizzle: 256 blocks, 8 XCDs -> each XCD gets 4 full M-rows of tiles
        const int wgid = (b & 7) * 32 + (b >> 3);
        const int bx = wgid & 7, by = wgid >> 3;   // bx: N-tile (8), by: M-tile (32)
        const int rA = by * 128, rB = bx * 128;
        const int wr = wv >> 2, wc = wv & 3;       // 2x4 waves -> WM=64, WN=32
        f32x4 acc[4][2] = {};
        for (int k0 = 0; k0 < 1024; k0 += 32) {
            GLOAD_LDS16(xb  + (size_t)(rA + (t >> 2)) * 1024 + k0 + (t & 3) * 8,
                        &lsA[wv * 512]);
            GLOAD_LDS16(Wfb + (size_t)(rB + (t >> 2)) * 1024 + k0 + (t & 3) * 8,
                        &lsB[wv * 512]);
            __syncthreads();
            bf16x8 af[4], bfv[2];
            #pragma unroll
            for (int i = 0; i < 4; ++i)
                af[i] = *(const bf16x8*)&lsA[(wr * 64 + i * 16 + fr) * 32 + fq * 8];
            #pragma unroll
            for (int j = 0; j < 2; ++j)
                bfv[j] = *(const bf16x8*)&lsB[(wc * 32 + j * 16 + fr) * 32 + fq * 8];
            #pragma unroll
            for (int i = 0; i < 4; ++i)
                #pragma unroll
                for (int j = 0; j < 2; ++j)
                    acc[i][j] = __builtin_amdgcn_mfma_f32_16x16x32_bf16(af[i], bfv[j], acc[i][j], 0, 0, 0);
            __syncthreads();
        }
        const int orow0 = rA + wr * 64 + fq * 4;
        const int ocol0 = rB + wc * 32 + fr;
        #pragma unroll
        for (int i = 0; i < 4; ++i)
            #pragma unroll
            for (int j = 0; j < 2; ++j) {
                const int col = ocol0 + j * 16;
                const float bv = bfused[col];
                #pragma unroll
                for (int r = 0; r < 4; ++r)
                    out[(size_t)(orow0 + i * 16 + r) * 1024 + col] = acc[i][j][r] + bv;
            }
    }
}

// ---------------------------------------------------------------------------
extern "C" void kernel_launch(void* const* d_in, const int* in_sizes, int n_in,
                              void* d_out, int out_size, void* d_ws, size_t ws_size,
                              hipStream_t stream) {
    const float* x     = (const float*)d_in[0];   // (2,2048,1024)
    const float* w_in  = (const float*)d_in[1];   // (3072,1024)
    const float* b_in  = (const float*)d_in[2];   // (3072,)
    const float* w_out = (const float*)d_in[3];   // (1024,1024)
    const float* b_out = (const float*)d_in[4];   // (1024,)
    float* out = (float*)d_out;                   // (2,2048,1024) fp32

    char* ws = (char*)d_ws;
    ushort_t* xb     = (ushort_t*)(ws);                      // 8 MB: x bf16
    ushort_t* wob    = (ushort_t*)(ws + (8u  << 20));        // 2 MB: w_out bf16
    ushort_t* Pt     = (ushort_t*)(ws + (10u << 20));        // 2 MB: w_in_v^T bf16
    ushort_t* Wfb    = (ushort_t*)(ws + (12u << 20));        // 2 MB: fused weight bf16
    float*    bfused = (float*)   (ws + (14u << 20));        // 4 KB

    void* args[] = {(void*)&x, (void*)&w_in, (void*)&b_in, (void*)&w_out, (void*)&b_out,
                    (void*)&xb, (void*)&wob, (void*)&Pt, (void*)&Wfb, (void*)&bfused,
                    (void*)&out};
    hipLaunchCooperativeKernel((const void*)fused, dim3(256), dim3(512), args, 0, stream);
}

// Round 4
// 40.207 us; speedup vs baseline: 2.9150x; 2.9150x over previous
//
#include <hip/hip_runtime.h>

typedef unsigned short ushort_t;
typedef __bf16 bf16x8 __attribute__((ext_vector_type(8)));
typedef float f32x4 __attribute__((ext_vector_type(4)));

static __device__ __forceinline__ ushort_t f2bf(float f) {
    __bf16 b = (__bf16)f;   // RNE convert
    return __builtin_bit_cast(ushort_t, b);
}

#define GLOAD_LDS16(gptr, lptr)                                                        \
    __builtin_amdgcn_global_load_lds(                                                  \
        (const __attribute__((address_space(1))) void*)(gptr),                         \
        (__attribute__((address_space(3))) void*)(lptr), 16, 0, 0)

#define CFENCE() asm volatile("" ::: "memory")

template <int N> __device__ __forceinline__ void waitcnt_vm() {
    if constexpr (N == 0) asm volatile("s_waitcnt vmcnt(0)" ::: "memory");
    else if constexpr (N == 2) asm volatile("s_waitcnt vmcnt(2)" ::: "memory");
    else if constexpr (N == 3) asm volatile("s_waitcnt vmcnt(3)" ::: "memory");
}

// ---------------------------------------------------------------------------
// Double-buffered GEMM core: C[M][N] = A[M][K] @ B[N][K]^T (+bias), bf16 in.
// 256 threads, 4 waves (2x2). BK=32. Counted-vmcnt prefetch (depth 1):
// loads for tile t+1 stay in flight across both barriers (never vmcnt(0)
// inside the loop). Raw s_barrier + compiler fences keep ds_reads/stores
// from crossing barriers at IR level.
template <int BM, int BN, bool BF16_OUT>
__device__ __forceinline__
void gemm_core(const ushort_t* __restrict__ A, const ushort_t* __restrict__ B,
               const float* __restrict__ bias, void* __restrict__ C,
               const int K, const int N, const int rA, const int rB,
               ushort_t* ls) {
    constexpr int WM = BM / 2, WN = BN / 2;
    constexpr int MI = WM / 16, NJ = WN / 16;
    constexpr int LA = (BM * 32) / (8 * 256);   // 16B chunks per thread (A)
    constexpr int LB = (BN * 32) / (8 * 256);
    constexpr int HALF = (BM + BN) * 32;        // ushorts per buffer

    const int tid  = threadIdx.x;
    const int lane = tid & 63;
    const int wv   = tid >> 6;
    const int wr   = wv >> 1, wc = wv & 1;
    const int fr   = lane & 15, fq = lane >> 4;

    f32x4 acc[MI][NJ] = {};

    auto stage = [&](int k0, int buf) {
        #pragma unroll
        for (int q = 0; q < LA; ++q) {
            int c = q * 256 + tid;
            GLOAD_LDS16(A + (size_t)(rA + (c >> 2)) * K + k0 + (c & 3) * 8,
                        &ls[buf * HALF + c * 8]);
        }
        #pragma unroll
        for (int q = 0; q < LB; ++q) {
            int c = q * 256 + tid;
            GLOAD_LDS16(B + (size_t)(rB + (c >> 2)) * K + k0 + (c & 3) * 8,
                        &ls[buf * HALF + BM * 32 + c * 8]);
        }
    };

    const int T = K >> 5;
    stage(0, 0);
    for (int t = 0; t < T; ++t) {
        const int cur = t & 1;
        if (t + 1 < T) {
            stage((t + 1) << 5, cur ^ 1);       // issue next tile's loads
            waitcnt_vm<LA + LB>();              // tile t landed; t+1 in flight
        } else {
            waitcnt_vm<0>();
        }
        __builtin_amdgcn_s_barrier();
        CFENCE();

        bf16x8 af[MI], bfv[NJ];
        #pragma unroll
        for (int i = 0; i < MI; ++i)
            af[i] = *(const bf16x8*)&ls[cur * HALF + (wr * WM + i * 16 + fr) * 32 + fq * 8];
        #pragma unroll
        for (int j = 0; j < NJ; ++j)
            bfv[j] = *(const bf16x8*)&ls[cur * HALF + BM * 32 + (wc * WN + j * 16 + fr) * 32 + fq * 8];
        #pragma unroll
        for (int i = 0; i < MI; ++i)
            #pragma unroll
            for (int j = 0; j < NJ; ++j)
                acc[i][j] = __builtin_amdgcn_mfma_f32_16x16x32_bf16(af[i], bfv[j], acc[i][j], 0, 0, 0);

        CFENCE();
        __builtin_amdgcn_s_barrier();           // reads of buf[cur] done before
        CFENCE();                               // next iter overwrites it
    }

    const int orow0 = rA + wr * WM + fq * 4;
    const int ocol0 = rB + wc * WN + fr;
    #pragma unroll
    for (int i = 0; i < MI; ++i)
        #pragma unroll
        for (int j = 0; j < NJ; ++j) {
            const int col = ocol0 + j * 16;
            const float bv = bias ? bias[col] : 0.f;
            #pragma unroll
            for (int r = 0; r < 4; ++r) {
                const int row = orow0 + i * 16 + r;
                const float v = acc[i][j][r] + bv;
                if constexpr (BF16_OUT)
                    ((ushort_t*)C)[(size_t)row * N + col] = f2bf(v);
                else
                    ((float*)C)[(size_t)row * N + col] = v;
            }
        }
}

// ---------------------------------------------------------------------------
// L1: small prep. blocks [0,128): w_out->bf16; [128,384): Pt gather;
//     [384,640): bfused rows.
__global__ __launch_bounds__(256)
void prep(const float* __restrict__ w_in, const float* __restrict__ b_in,
          const float* __restrict__ w_out, const float* __restrict__ b_out,
          ushort_t* __restrict__ wob, ushort_t* __restrict__ Pt,
          float* __restrict__ bfused) {
    __shared__ ushort_t tile[64][65];
    const int b = blockIdx.x;
    const int t = threadIdx.x;

    if (b < 128) {
        #pragma unroll
        for (int p = 0; p < 8; ++p) {
            int i = b * 2048 + p * 256 + t;
            float4 v = ((const float4*)w_out)[i];
            ushort4 o; o.x = f2bf(v.x); o.y = f2bf(v.y); o.z = f2bf(v.z); o.w = f2bf(v.w);
            ((ushort4*)wob)[i] = o;
        }
    } else if (b < 384) {
        const int g = b - 128;
        const int gx = g & 15, gy = g >> 4;
        #pragma unroll
        for (int p = 0; p < 16; ++p) {
            int e = p * 256 + t;
            int j = e >> 6, c = e & 63;
            tile[j][c] = f2bf(w_in[(size_t)(gx * 192 + 128 + j) * 1024 + gy * 64 + c]);
        }
        __syncthreads();
        #pragma unroll
        for (int p = 0; p < 16; ++p) {
            int e = p * 256 + t;
            int c = e >> 6, j = e & 63;
            Pt[(size_t)(gy * 64 + c) * 1024 + gx * 64 + j] = tile[j][c];
        }
    } else {
        const int w = t >> 6, lane = t & 63;
        const int row = (b - 384) * 4 + w;
        float s = 0.f;
        #pragma unroll
        for (int it = 0; it < 16; ++it) {
            int j = it * 64 + lane;
            int r = (j >> 6) * 192 + 128 + (j & 63);
            s += w_out[(size_t)row * 1024 + j] * b_in[r];
        }
        #pragma unroll
        for (int off = 32; off; off >>= 1) s += __shfl_down(s, off, 64);
        if (lane == 0) bfused[row] = s + b_out[row];
    }
}

// ---------------------------------------------------------------------------
// L2: blocks [0,256): Wf = wob @ Pt^T (64x64 tiles, XCD-swizzled);
//     blocks [256,768): x fp32 -> bf16 (independent, overlaps the GEMM).
__global__ __launch_bounds__(256)
void k2(const ushort_t* __restrict__ wob, const ushort_t* __restrict__ Pt,
        ushort_t* __restrict__ Wfb,
        const float* __restrict__ x, ushort_t* __restrict__ xb) {
    __shared__ alignas(16) ushort_t ls[(64 + 64) * 32 * 2];
    const int b = blockIdx.x;
    if (b < 256) {
        const int swz = (b & 7) * 32 + (b >> 3);
        const int by = swz >> 4, bx = swz & 15;
        gemm_core<64, 64, true>(wob, Pt, nullptr, (void*)Wfb, 1024, 1024,
                                by * 64, bx * 64, ls);
    } else {
        const int g = b - 256;
        const int t = threadIdx.x;
        #pragma unroll
        for (int p = 0; p < 8; ++p) {
            int i = g * 2048 + p * 256 + t;
            float4 v = ((const float4*)x)[i];
            ushort4 o; o.x = f2bf(v.x); o.y = f2bf(v.y); o.z = f2bf(v.z); o.w = f2bf(v.w);
            ((ushort4*)xb)[i] = o;
        }
    }
}

// ---------------------------------------------------------------------------
// L3: out = xb @ Wfb^T + bfused. 128x64 tiles -> 512 blocks (2/CU),
//     XCD-swizzled so each XCD owns 4 contiguous M-panels.
__global__ __launch_bounds__(256)
void k3(const ushort_t* __restrict__ xb, const ushort_t* __restrict__ Wfb,
        const float* __restrict__ bfused, float* __restrict__ out) {
    __shared__ alignas(16) ushort_t ls[(128 + 64) * 32 * 2];
    const int b = blockIdx.x;
    const int swz = (b & 7) * 64 + (b >> 3);
    const int by = swz >> 4, bx = swz & 15;     // by: 32 M-tiles, bx: 16 N-tiles
    gemm_core<128, 64, false>(xb, Wfb, bfused, (void*)out, 1024, 1024,
                              by * 128, bx * 64, ls);
}

// ---------------------------------------------------------------------------
extern "C" void kernel_launch(void* const* d_in, const int* in_sizes, int n_in,
                              void* d_out, int out_size, void* d_ws, size_t ws_size,
                              hipStream_t stream) {
    const float* x     = (const float*)d_in[0];   // (2,2048,1024)
    const float* w_in  = (const float*)d_in[1];   // (3072,1024)
    const float* b_in  = (const float*)d_in[2];   // (3072,)
    const float* w_out = (const float*)d_in[3];   // (1024,1024)
    const float* b_out = (const float*)d_in[4];   // (1024,)
    float* out = (float*)d_out;                   // (2,2048,1024) fp32

    char* ws = (char*)d_ws;
    ushort_t* xb     = (ushort_t*)(ws);                      // 8 MB
    ushort_t* wob    = (ushort_t*)(ws + (8u  << 20));        // 2 MB
    ushort_t* Pt     = (ushort_t*)(ws + (10u << 20));        // 2 MB
    ushort_t* Wfb    = (ushort_t*)(ws + (12u << 20));        // 2 MB
    float*    bfused = (float*)   (ws + (14u << 20));        // 4 KB

    prep<<<640, 256, 0, stream>>>(w_in, b_in, w_out, b_out, wob, Pt, bfused);
    k2<<<768, 256, 0, stream>>>(wob, Pt, Wfb, x, xb);
    k3<<<512, 256, 0, stream>>>(xb, Wfb, bfused, out);
}

// Round 5
// 37.225 us; speedup vs baseline: 3.1485x; 1.0801x over previous
//
#include <hip/hip_runtime.h>

typedef unsigned short ushort_t;
typedef __bf16 bf16x8 __attribute__((ext_vector_type(8)));
typedef float f32x4 __attribute__((ext_vector_type(4)));

static __device__ __forceinline__ ushort_t f2bf(float f) {
    __bf16 b = (__bf16)f;   // RNE convert
    return __builtin_bit_cast(ushort_t, b);
}

#define GLOAD_LDS16(gptr, lptr)                                                        \
    __builtin_amdgcn_global_load_lds(                                                  \
        (const __attribute__((address_space(1))) void*)(gptr),                         \
        (__attribute__((address_space(3))) void*)(lptr), 16, 0, 0)

#define CFENCE() asm volatile("" ::: "memory")

template <int N> __device__ __forceinline__ void waitcnt_vm() {
    if constexpr (N == 0)      asm volatile("s_waitcnt vmcnt(0)" ::: "memory");
    else if constexpr (N == 2) asm volatile("s_waitcnt vmcnt(2)" ::: "memory");
    else if constexpr (N == 4) asm volatile("s_waitcnt vmcnt(4)" ::: "memory");
    else if constexpr (N == 8) asm volatile("s_waitcnt vmcnt(8)" ::: "memory");
}

// ---------------------------------------------------------------------------
// Triple-buffered GEMM core: C[M][N] = A[M][K] @ B[N][K]^T (+bias), bf16 in.
// 256 threads, 4 waves (WGM x WGN). BK=32. Depth-2 counted-vmcnt prefetch:
// tiles t+1, t+2 stay in flight; steady-state wait is vmcnt(2L), never 0.
template <int BM, int BN, int WGM, int WGN, bool BF16_OUT>
__device__ __forceinline__
void gemm_core(const ushort_t* __restrict__ A, const ushort_t* __restrict__ B,
               const float* __restrict__ bias, void* __restrict__ C,
               const int K, const int N, const int rA, const int rB,
               ushort_t* ls) {
    constexpr int WM = BM / WGM, WN = BN / WGN;
    constexpr int MI = WM / 16, NJ = WN / 16;
    constexpr int LA = (BM * 32) / (8 * 256);   // 16B chunks per thread (A)
    constexpr int LB = (BN * 32) / (8 * 256);
    constexpr int L  = LA + LB;
    constexpr int HALF = (BM + BN) * 32;        // ushorts per buffer

    const int tid  = threadIdx.x;
    const int lane = tid & 63;
    const int wv   = tid >> 6;
    const int wr   = wv / WGN, wc = wv % WGN;
    const int fr   = lane & 15, fq = lane >> 4;

    f32x4 acc[MI][NJ] = {};

    auto stage = [&](int k0, int buf) {
        #pragma unroll
        for (int q = 0; q < LA; ++q) {
            int c = q * 256 + tid;
            GLOAD_LDS16(A + (size_t)(rA + (c >> 2)) * K + k0 + (c & 3) * 8,
                        &ls[buf * HALF + c * 8]);
        }
        #pragma unroll
        for (int q = 0; q < LB; ++q) {
            int c = q * 256 + tid;
            GLOAD_LDS16(B + (size_t)(rB + (c >> 2)) * K + k0 + (c & 3) * 8,
                        &ls[buf * HALF + BM * 32 + c * 8]);
        }
    };

    auto compute = [&](int buf) {
        bf16x8 af[MI], bfv[NJ];
        #pragma unroll
        for (int i = 0; i < MI; ++i)
            af[i] = *(const bf16x8*)&ls[buf * HALF + (wr * WM + i * 16 + fr) * 32 + fq * 8];
        #pragma unroll
        for (int j = 0; j < NJ; ++j)
            bfv[j] = *(const bf16x8*)&ls[buf * HALF + BM * 32 + (wc * WN + j * 16 + fr) * 32 + fq * 8];
        #pragma unroll
        for (int i = 0; i < MI; ++i)
            #pragma unroll
            for (int j = 0; j < NJ; ++j)
                acc[i][j] = __builtin_amdgcn_mfma_f32_16x16x32_bf16(af[i], bfv[j], acc[i][j], 0, 0, 0);
    };

    const int T = K >> 5;                        // requires T >= 3
    stage(0, 0);
    stage(32, 1);
    int cur = 0, nxt2 = 2;
    for (int t = 0; t < T - 2; ++t) {
        stage((t + 2) << 5, nxt2);               // issue tile t+2
        waitcnt_vm<2 * L>();                     // tile t landed; t+1,t+2 in flight
        __builtin_amdgcn_s_barrier(); CFENCE();
        compute(cur);
        CFENCE(); __builtin_amdgcn_s_barrier(); CFENCE();
        cur  = (cur  + 1 == 3) ? 0 : cur  + 1;
        nxt2 = (nxt2 + 1 == 3) ? 0 : nxt2 + 1;
    }
    waitcnt_vm<L>();                             // tile T-2 landed
    __builtin_amdgcn_s_barrier(); CFENCE();
    compute(cur);
    cur = (cur + 1 == 3) ? 0 : cur + 1;
    CFENCE();
    waitcnt_vm<0>();                             // tile T-1 landed
    __builtin_amdgcn_s_barrier(); CFENCE();
    compute(cur);

    const int orow0 = rA + wr * WM + fq * 4;
    const int ocol0 = rB + wc * WN + fr;
    #pragma unroll
    for (int i = 0; i < MI; ++i)
        #pragma unroll
        for (int j = 0; j < NJ; ++j) {
            const int col = ocol0 + j * 16;
            const float bv = bias ? bias[col] : 0.f;
            #pragma unroll
            for (int r = 0; r < 4; ++r) {
                const int row = orow0 + i * 16 + r;
                const float v = acc[i][j][r] + bv;
                if constexpr (BF16_OUT)
                    ((ushort_t*)C)[(size_t)row * N + col] = f2bf(v);
                else
                    ((float*)C)[(size_t)row * N + col] = v;
            }
        }
}

// ---------------------------------------------------------------------------
// L1: small prep. blocks [0,128): w_out->bf16; [128,384): Pt gather;
//     [384,640): bfused rows.
__global__ __launch_bounds__(256)
void prep(const float* __restrict__ w_in, const float* __restrict__ b_in,
          const float* __restrict__ w_out, const float* __restrict__ b_out,
          ushort_t* __restrict__ wob, ushort_t* __restrict__ Pt,
          float* __restrict__ bfused) {
    __shared__ ushort_t tile[64][65];
    const int b = blockIdx.x;
    const int t = threadIdx.x;

    if (b < 128) {
        #pragma unroll
        for (int p = 0; p < 8; ++p) {
            int i = b * 2048 + p * 256 + t;
            float4 v = ((const float4*)w_out)[i];
            ushort4 o; o.x = f2bf(v.x); o.y = f2bf(v.y); o.z = f2bf(v.z); o.w = f2bf(v.w);
            ((ushort4*)wob)[i] = o;
        }
    } else if (b < 384) {
        const int g = b - 128;
        const int gx = g & 15, gy = g >> 4;
        #pragma unroll
        for (int p = 0; p < 16; ++p) {
            int e = p * 256 + t;
            int j = e >> 6, c = e & 63;
            tile[j][c] = f2bf(w_in[(size_t)(gx * 192 + 128 + j) * 1024 + gy * 64 + c]);
        }
        __syncthreads();
        #pragma unroll
        for (int p = 0; p < 16; ++p) {
            int e = p * 256 + t;
            int c = e >> 6, j = e & 63;
            Pt[(size_t)(gy * 64 + c) * 1024 + gx * 64 + j] = tile[j][c];
        }
    } else {
        const int w = t >> 6, lane = t & 63;
        const int row = (b - 384) * 4 + w;
        float s = 0.f;
        #pragma unroll
        for (int it = 0; it < 16; ++it) {
            int j = it * 64 + lane;
            int r = (j >> 6) * 192 + 128 + (j & 63);
            s += w_out[(size_t)row * 1024 + j] * b_in[r];
        }
        #pragma unroll
        for (int off = 32; off; off >>= 1) s += __shfl_down(s, off, 64);
        if (lane == 0) bfused[row] = s + b_out[row];
    }
}

// ---------------------------------------------------------------------------
// L2: blocks [0,256): Wf = wob @ Pt^T (64x64 tiles, XCD-swizzled);
//     blocks [256,768): x fp32 -> bf16 (independent, overlaps the GEMM).
__global__ __launch_bounds__(256)
void k2(const ushort_t* __restrict__ wob, const ushort_t* __restrict__ Pt,
        ushort_t* __restrict__ Wfb,
        const float* __restrict__ x, ushort_t* __restrict__ xb) {
    __shared__ alignas(16) ushort_t ls[3 * (64 + 64) * 32];
    const int b = blockIdx.x;
    if (b < 256) {
        const int swz = (b & 7) * 32 + (b >> 3);
        const int by = swz >> 4, bx = swz & 15;
        gemm_core<64, 64, 2, 2, true>(wob, Pt, nullptr, (void*)Wfb, 1024, 1024,
                                      by * 64, bx * 64, ls);
    } else {
        const int g = b - 256;
        const int t = threadIdx.x;
        #pragma unroll
        for (int p = 0; p < 8; ++p) {
            int i = g * 2048 + p * 256 + t;
            float4 v = ((const float4*)x)[i];
            ushort4 o; o.x = f2bf(v.x); o.y = f2bf(v.y); o.z = f2bf(v.z); o.w = f2bf(v.w);
            ((ushort4*)xb)[i] = o;
        }
    }
}

// ---------------------------------------------------------------------------
// L3: out = xb @ Wfb^T + bfused. 128x128 tiles (per-wave 64x64) -> 256 blocks
//     (1/CU), triple-buffered. XCD-swizzled: each XCD owns 4 M-panels.
__global__ __launch_bounds__(256)
void k3(const ushort_t* __restrict__ xb, const ushort_t* __restrict__ Wfb,
        const float* __restrict__ bfused, float* __restrict__ out) {
    __shared__ alignas(16) ushort_t ls[3 * (128 + 128) * 32];
    const int b = blockIdx.x;
    const int swz = (b & 7) * 32 + (b >> 3);
    const int by = swz >> 3, bx = swz & 7;      // 32 M-tiles x 8 N-tiles
    gemm_core<128, 128, 2, 2, false>(xb, Wfb, bfused, (void*)out, 1024, 1024,
                                     by * 128, bx * 128, ls);
}

// ---------------------------------------------------------------------------
extern "C" void kernel_launch(void* const* d_in, const int* in_sizes, int n_in,
                              void* d_out, int out_size, void* d_ws, size_t ws_size,
                              hipStream_t stream) {
    const float* x     = (const float*)d_in[0];   // (2,2048,1024)
    const float* w_in  = (const float*)d_in[1];   // (3072,1024)
    const float* b_in  = (const float*)d_in[2];   // (3072,)
    const float* w_out = (const float*)d_in[3];   // (1024,1024)
    const float* b_out = (const float*)d_in[4];   // (1024,)
    float* out = (float*)d_out;                   // (2,2048,1024) fp32

    char* ws = (char*)d_ws;
    ushort_t* xb     = (ushort_t*)(ws);                      // 8 MB
    ushort_t* wob    = (ushort_t*)(ws + (8u  << 20));        // 2 MB
    ushort_t* Pt     = (ushort_t*)(ws + (10u << 20));        // 2 MB
    ushort_t* Wfb    = (ushort_t*)(ws + (12u << 20));        // 2 MB
    float*    bfused = (float*)   (ws + (14u << 20));        // 4 KB

    prep<<<640, 256, 0, stream>>>(w_in, b_in, w_out, b_out, wob, Pt, bfused);
    k2<<<768, 256, 0, stream>>>(wob, Pt, Wfb, x, xb);
    k3<<<256, 256, 0, stream>>>(xb, Wfb, bfused, out);
}